// Round 1
// 552.745 us; speedup vs baseline: 1.0139x; 1.0139x over previous
//
#include <hip/hip_runtime.h>
#include <hip/hip_bf16.h>

#define N_ 8192
#define F_ 256
#define H_ 128
#define L_ 32
#define TK 64
#define KQN 4
#define KQL (N_ / KQN)   // 2048

typedef __attribute__((ext_vector_type(8))) short bf16x8;
typedef __attribute__((ext_vector_type(4))) float f32x4;
typedef __attribute__((ext_vector_type(4))) short bf16x4;

// RNE float -> bf16 (finite inputs only)
__device__ __forceinline__ unsigned f2bf_u(float x) {
    unsigned u = __builtin_bit_cast(unsigned, x);
    return (u + 0x7fffu + ((u >> 16) & 1u)) >> 16;
}
__device__ __forceinline__ short f2bf(float x) { return (short)f2bf_u(x); }

__device__ __forceinline__ bf16x4 cvt4(float4 a) {
    bf16x4 v;
    v[0] = f2bf(a.x); v[1] = f2bf(a.y); v[2] = f2bf(a.z); v[3] = f2bf(a.w);
    return v;
}
__device__ __forceinline__ bf16x8 cvt8(float4 a, float4 b) {
    bf16x8 v;
    v[0] = f2bf(a.x); v[1] = f2bf(a.y); v[2] = f2bf(a.z); v[3] = f2bf(a.w);
    v[4] = f2bf(b.x); v[5] = f2bf(b.y); v[6] = f2bf(b.z); v[7] = f2bf(b.w);
    return v;
}

// ---------------------------------------------------------------------------
// k1: XW1T[n][i] = (X @ W1)[i][n], bf16.  64 rows/block, 4 waves x 16 rows.
// ---------------------------------------------------------------------------
__global__ __launch_bounds__(256) void k1_xw1(const float* __restrict__ X,
                                              const float* __restrict__ W1,
                                              short* __restrict__ XW1T) {
    __shared__ short w1t[H_ * (F_ + 8)];
    const int tid = threadIdx.x;
    for (int idx = tid; idx < F_ * H_; idx += 256) {
        int k = idx >> 7, n = idx & 127;
        w1t[n * (F_ + 8) + k] = f2bf(W1[idx]);
    }
    __syncthreads();
    const int wv = tid >> 6, l = tid & 63;
    const int lm = l & 15, q = l >> 4;
    const int i0 = blockIdx.x * 64 + wv * 16;
    const float* xrow = X + (size_t)(i0 + lm) * F_;
    f32x4 acc[8];
#pragma unroll
    for (int j = 0; j < 8; ++j) acc[j] = (f32x4){0.f, 0.f, 0.f, 0.f};
#pragma unroll
    for (int k0 = 0; k0 < F_; k0 += 32) {
        float4 a0 = *(const float4*)(xrow + k0 + q * 8);
        float4 a1 = *(const float4*)(xrow + k0 + q * 8 + 4);
        bf16x8 af = cvt8(a0, a1);
#pragma unroll
        for (int j = 0; j < 8; ++j) {
            bf16x8 bf = *(const bf16x8*)&w1t[(j * 16 + lm) * (F_ + 8) + k0 + q * 8];
            acc[j] = __builtin_amdgcn_mfma_f32_16x16x32_bf16(af, bf, acc[j], 0, 0, 0);
        }
    }
#pragma unroll
    for (int j = 0; j < 8; ++j) {
        bf16x4 o;
        o[0] = f2bf(acc[j][0]); o[1] = f2bf(acc[j][1]);
        o[2] = f2bf(acc[j][2]); o[3] = f2bf(acc[j][3]);
        *(bf16x4*)(XW1T + (size_t)(j * 16 + lm) * N_ + i0 + q * 4) = o;
    }
}

// ---------------------------------------------------------------------------
// k2a: P4[kq][i][n] += A[i, kq-slice] @ XW1[kq-slice, n]  (fp32 partials)
// 512 blocks = 128 row-tiles(64) x 4 K-quarters; 8 waves.
// Issue-early / write-late: two named reg sets, loads at top of each half.
// WRITE_AB: also stream out bf16 copy of A (for k3a to reuse, L3-resident).
// ---------------------------------------------------------------------------
template <int WRITE_AB>
__global__ __launch_bounds__(512) void k2a(const float* __restrict__ A,
                                           const short* __restrict__ XW1T,
                                           float* __restrict__ P4,
                                           short* __restrict__ Ab) {
    __shared__ short As[2][64][72];    // 18.4 KB
    __shared__ short Bs[2][128][72];   // 36.9 KB
    const int tid = threadIdx.x;
    const int bi = blockIdx.x >> 2, kq = blockIdx.x & 3;
    const int i0 = bi * 64, kbase = kq * KQL;
    // staging coords: A 64x64 fp32, thread does rows ar, ar+32 (float4 each)
    const int ar = tid >> 4, ac = (tid & 15) * 4;
    // B 128x64 bf16, thread does rows br, br+64 (bf16x8 each)
    const int br = tid >> 3, bc = (tid & 7) * 8;
    const float* Ap = A + (size_t)(i0 + ar) * N_ + kbase + ac;
    const short* Bp = XW1T + (size_t)br * N_ + kbase + bc;
    short* Abp = Ab + (size_t)(i0 + ar) * N_ + kbase + ac;

    const int wv = tid >> 6, l = tid & 63, lm = l & 15, q = l >> 4;
    const int rg = wv & 3, ch = wv >> 2;   // 4 row-groups x 2 col-halves

    float4 Pa0, Pa1; bf16x8 Pb0, Pb1;   // reg set P
    float4 Qa0, Qa1; bf16x8 Qb0, Qb1;   // reg set Q

#define LOADG2(S, o_) do { size_t _o = (size_t)(o_) * TK; \
        S##a0 = *(const float4*)(Ap + _o); \
        S##a1 = *(const float4*)(Ap + _o + (size_t)32 * N_); \
        S##b0 = *(const bf16x8*)(Bp + _o); \
        S##b1 = *(const bf16x8*)(Bp + _o + (size_t)64 * N_); } while (0)
#define STORES2(S, b_, o_) do { \
        bf16x4 _c0 = cvt4(S##a0), _c1 = cvt4(S##a1); \
        *(bf16x4*)&As[b_][ar][ac] = _c0; \
        *(bf16x4*)&As[b_][ar + 32][ac] = _c1; \
        *(bf16x8*)&Bs[b_][br][bc] = S##b0; \
        *(bf16x8*)&Bs[b_][br + 64][bc] = S##b1; \
        if (WRITE_AB) { size_t _o = (size_t)(o_) * TK; \
            *(bf16x4*)(Abp + _o) = _c0; \
            *(bf16x4*)(Abp + _o + (size_t)32 * N_) = _c1; } } while (0)
#define MFMAPH2(b_) do { \
        for (int kh = 0; kh < 2; ++kh) { \
            bf16x8 af = *(const bf16x8*)&As[b_][rg * 16 + lm][kh * 32 + q * 8]; \
            for (int jt = 0; jt < 4; ++jt) { \
                bf16x8 bfv = *(const bf16x8*)&Bs[b_][ch * 64 + jt * 16 + lm][kh * 32 + q * 8]; \
                acc[jt] = __builtin_amdgcn_mfma_f32_16x16x32_bf16(af, bfv, acc[jt], 0, 0, 0); \
            } } } while (0)

    LOADG2(P, 0); STORES2(P, 0, 0); LOADG2(Q, 1);
    __syncthreads();

    f32x4 acc[4];
#pragma unroll
    for (int j = 0; j < 4; ++j) acc[j] = (f32x4){0.f, 0.f, 0.f, 0.f};
    const int NS = KQL / TK;   // 32
    for (int s = 0; s < NS; s += 2) {
        if (s + 2 < NS) LOADG2(P, s + 2);
        MFMAPH2(0);
        STORES2(Q, 1, s + 1);
        __syncthreads();
        if (s + 3 < NS) LOADG2(Q, s + 3);
        MFMAPH2(1);
        if (s + 2 < NS) STORES2(P, 0, s + 2);
        __syncthreads();
    }
#undef LOADG2
#undef STORES2
#undef MFMAPH2
    // store partials: row = i0+rg*16+q*4+r, col = ch*64+jt*16+lm
    float* Pb = P4 + ((size_t)kq * N_ + i0 + rg * 16 + q * 4) * H_ + ch * 64 + lm;
#pragma unroll
    for (int jt = 0; jt < 4; ++jt)
#pragma unroll
        for (int r = 0; r < 4; ++r)
            Pb[(size_t)r * H_ + jt * 16] = acc[jt][r];
}

// ---------------------------------------------------------------------------
// k2b: ZPT[j][i] = ((relu(sum_kq P4)) @ W2)[i][j], bf16. 32 rows/block.
// ---------------------------------------------------------------------------
__global__ __launch_bounds__(256) void k2b(const float* __restrict__ P4,
                                           const float* __restrict__ W2,
                                           short* __restrict__ ZPT) {
    __shared__ short hl[32][136];
    __shared__ short w2t[32][136];
    const int tid = threadIdx.x;
    for (int idx = tid; idx < H_ * L_; idx += 256) {
        int k = idx >> 5, j = idx & 31;
        w2t[j][k] = f2bf(W2[idx]);
    }
    const int i0 = blockIdx.x * 32;
    const int r = tid >> 3, c16 = (tid & 7) * 16;
    float4 v[4];
#pragma unroll
    for (int cc = 0; cc < 4; ++cc) v[cc] = (float4){0.f, 0.f, 0.f, 0.f};
#pragma unroll
    for (int kq = 0; kq < 4; ++kq) {
        const float* p = P4 + ((size_t)kq * N_ + i0 + r) * H_ + c16;
#pragma unroll
        for (int cc = 0; cc < 4; ++cc) {
            float4 t = *(const float4*)(p + cc * 4);
            v[cc].x += t.x; v[cc].y += t.y; v[cc].z += t.z; v[cc].w += t.w;
        }
    }
#pragma unroll
    for (int cc = 0; cc < 4; ++cc) {
        v[cc].x = v[cc].x > 0.f ? v[cc].x : 0.f;
        v[cc].y = v[cc].y > 0.f ? v[cc].y : 0.f;
        v[cc].z = v[cc].z > 0.f ? v[cc].z : 0.f;
        v[cc].w = v[cc].w > 0.f ? v[cc].w : 0.f;
    }
    *(bf16x8*)&hl[r][c16] = cvt8(v[0], v[1]);
    *(bf16x8*)&hl[r][c16 + 8] = cvt8(v[2], v[3]);
    __syncthreads();
    const int wv = tid >> 6, l = tid & 63, lm = l & 15, q = l >> 4;
    const int ti = wv & 1, tj = wv >> 1;
    f32x4 a2 = (f32x4){0.f, 0.f, 0.f, 0.f};
#pragma unroll
    for (int k0 = 0; k0 < H_; k0 += 32) {
        bf16x8 af = *(const bf16x8*)&hl[ti * 16 + lm][k0 + q * 8];
        bf16x8 bf = *(const bf16x8*)&w2t[tj * 16 + lm][k0 + q * 8];
        a2 = __builtin_amdgcn_mfma_f32_16x16x32_bf16(af, bf, a2, 0, 0, 0);
    }
    bf16x4 o;
    o[0] = f2bf(a2[0]); o[1] = f2bf(a2[1]); o[2] = f2bf(a2[2]); o[3] = f2bf(a2[3]);
    *(bf16x4*)(ZPT + (size_t)(tj * 16 + lm) * N_ + i0 + ti * 16 + q * 4) = o;
}

// ---------------------------------------------------------------------------
// k3a_bf: Q4[kq][i][j] += Ab[i, kq-slice] @ ZP[kq-slice, j]; A already bf16.
// Same schedule as k2a (issue-early / write-late).
// ---------------------------------------------------------------------------
__global__ __launch_bounds__(512) void k3a_bf(const short* __restrict__ Ab,
                                              const short* __restrict__ ZPT,
                                              float* __restrict__ Q4) {
    __shared__ short As[2][64][72];   // 18.4 KB
    __shared__ short Bs[2][32][72];   // 9.2 KB
    const int tid = threadIdx.x;
    const int bi = blockIdx.x >> 2, kq = blockIdx.x & 3;
    const int i0 = bi * 64, kbase = kq * KQL;
    const int ar8 = tid >> 3, ac8 = (tid & 7) * 8;   // A: 64 rows x 64 bf16, bf16x8 each
    const int br = tid >> 4, bc = (tid & 15) * 4;    // B: 32 rows x 64 bf16, bf16x4 each
    const short* Ap = Ab + (size_t)(i0 + ar8) * N_ + kbase + ac8;
    const short* Bp = ZPT + (size_t)br * N_ + kbase + bc;

    const int wv = tid >> 6, l = tid & 63, lm = l & 15, q = l >> 4;
    const int rg = wv & 3, ch = wv >> 2;   // 4 row-groups x 2 col-halves(16)

    bf16x8 Pa; bf16x4 Pb;
    bf16x8 Qa; bf16x4 Qb;

#define LOADG3(S, o_) do { size_t _o = (size_t)(o_) * TK; \
        S##a = *(const bf16x8*)(Ap + _o); \
        S##b = *(const bf16x4*)(Bp + _o); } while (0)
#define STORES3(S, b_) do { \
        *(bf16x8*)&As[b_][ar8][ac8] = S##a; \
        *(bf16x4*)&Bs[b_][br][bc] = S##b; } while (0)
#define MFMAPH3(b_) do { \
        for (int kh = 0; kh < 2; ++kh) { \
            bf16x8 af = *(const bf16x8*)&As[b_][rg * 16 + lm][kh * 32 + q * 8]; \
            bf16x8 bfv = *(const bf16x8*)&Bs[b_][ch * 16 + lm][kh * 32 + q * 8]; \
            acc = __builtin_amdgcn_mfma_f32_16x16x32_bf16(af, bfv, acc, 0, 0, 0); \
        } } while (0)

    LOADG3(P, 0); STORES3(P, 0); LOADG3(Q, 1);
    __syncthreads();

    f32x4 acc = (f32x4){0.f, 0.f, 0.f, 0.f};
    const int NS = KQL / TK;   // 32
    for (int s = 0; s < NS; s += 2) {
        if (s + 2 < NS) LOADG3(P, s + 2);
        MFMAPH3(0);
        STORES3(Q, 1);
        __syncthreads();
        if (s + 3 < NS) LOADG3(Q, s + 3);
        MFMAPH3(1);
        if (s + 2 < NS) STORES3(P, 0);
        __syncthreads();
    }
#undef LOADG3
#undef STORES3
#undef MFMAPH3
    float* Qb_ = Q4 + ((size_t)kq * N_ + i0 + rg * 16 + q * 4) * L_ + ch * 16 + lm;
#pragma unroll
    for (int r = 0; r < 4; ++r)
        Qb_[(size_t)r * L_] = acc[r];
}

// ---------------------------------------------------------------------------
// k3a_f32: fallback (workspace too small for Ab) — reads fp32 A, original code.
// ---------------------------------------------------------------------------
__global__ __launch_bounds__(512) void k3a_f32(const float* __restrict__ A,
                                               const short* __restrict__ ZPT,
                                               float* __restrict__ Q4) {
    __shared__ short As[2][64][72];
    __shared__ short Bs[2][32][72];
    const int tid = threadIdx.x;
    const int bi = blockIdx.x >> 2, kq = blockIdx.x & 3;
    const int i0 = bi * 64, kbase = kq * KQL;
    const int ar = tid >> 4, ac = (tid & 15) * 4;
    const int br = tid >> 4, bc = (tid & 15) * 4;
    const float* Ap = A + (size_t)(i0 + ar) * N_ + kbase + ac;
    const short* Bp = ZPT + (size_t)br * N_ + kbase + bc;

    const int wv = tid >> 6, l = tid & 63, lm = l & 15, q = l >> 4;
    const int rg = wv & 3, ch = wv >> 2;

    float4 pa0, pa1; bf16x4 pb0;
#define LOADG0(s) do { size_t o = (size_t)(s) * TK; \
        pa0 = *(const float4*)(Ap + o); \
        pa1 = *(const float4*)(Ap + o + (size_t)32 * N_); \
        pb0 = *(const bf16x4*)(Bp + o); } while (0)
#define STORES0(b) do { \
        *(bf16x4*)&As[b][ar][ac] = cvt4(pa0); \
        *(bf16x4*)&As[b][ar + 32][ac] = cvt4(pa1); \
        *(bf16x4*)&Bs[b][br][bc] = pb0; } while (0)

    LOADG0(0); STORES0(0); LOADG0(1);
    __syncthreads();

    f32x4 acc = (f32x4){0.f, 0.f, 0.f, 0.f};
    const int NS = KQL / TK;
#pragma unroll 2
    for (int s = 0; s < NS; ++s) {
        const int b = s & 1;
#pragma unroll
        for (int kh = 0; kh < 2; ++kh) {
            bf16x8 af = *(const bf16x8*)&As[b][rg * 16 + lm][kh * 32 + q * 8];
            bf16x8 bfv = *(const bf16x8*)&Bs[b][ch * 16 + lm][kh * 32 + q * 8];
            acc = __builtin_amdgcn_mfma_f32_16x16x32_bf16(af, bfv, acc, 0, 0, 0);
        }
        if (s + 1 < NS) {
            STORES0((s + 1) & 1);
            if (s + 2 < NS) LOADG0(s + 2);
        }
        __syncthreads();
    }
#undef LOADG0
#undef STORES0
    float* Qb = Q4 + ((size_t)kq * N_ + i0 + rg * 16 + q * 4) * L_ + ch * 16 + lm;
#pragma unroll
    for (int r = 0; r < 4; ++r)
        Qb[(size_t)r * L_] = acc[r];
}

// ---------------------------------------------------------------------------
// k3b: Z = bf16(sum_kq Q4), flat elementwise.
// ---------------------------------------------------------------------------
__global__ __launch_bounds__(256) void k3b(const float* __restrict__ Q4,
                                           short* __restrict__ Z) {
    size_t g = ((size_t)blockIdx.x * 256 + threadIdx.x) * 8;
    float4 s0 = (float4){0.f, 0.f, 0.f, 0.f}, s1 = s0;
#pragma unroll
    for (int kq = 0; kq < 4; ++kq) {
        const float* p = Q4 + (size_t)kq * N_ * L_ + g;
        float4 a = *(const float4*)(p);
        float4 b = *(const float4*)(p + 4);
        s0.x += a.x; s0.y += a.y; s0.z += a.z; s0.w += a.w;
        s1.x += b.x; s1.y += b.y; s1.z += b.z; s1.w += b.w;
    }
    *(bf16x8*)(Z + g) = cvt8(s0, s1);
}

// ---------------------------------------------------------------------------
// k4: out = sigmoid(Z @ Z^T). 64x128/block (33.8 KB LDS -> 4 blocks/CU);
// sigmoid -> LDS -> coalesced float4 stores.
// ---------------------------------------------------------------------------
__global__ __launch_bounds__(256) void k4_dec(const short* __restrict__ Z,
                                              float* __restrict__ out) {
    __shared__ float os[64][132];   // 33.8 KB
    const int tid = threadIdx.x;
    const int wv = tid >> 6, l = tid & 63;
    const int lm = l & 15, q = l >> 4;
    const int bj = blockIdx.x & 63, bi = blockIdx.x >> 6;
    const int i0 = bi * 64, j0 = bj * 128;
    bf16x8 af = *(const bf16x8*)(Z + (size_t)(i0 + wv * 16 + lm) * L_ + q * 8);
#pragma unroll
    for (int tj = 0; tj < 8; ++tj) {
        bf16x8 bfv = *(const bf16x8*)(Z + (size_t)(j0 + tj * 16 + lm) * L_ + q * 8);
        f32x4 c = __builtin_amdgcn_mfma_f32_16x16x32_bf16(
            af, bfv, (f32x4){0.f, 0.f, 0.f, 0.f}, 0, 0, 0);
#pragma unroll
        for (int r = 0; r < 4; ++r) {
            float e = __expf(-c[r]);
            os[wv * 16 + q * 4 + r][tj * 16 + lm] = __fdividef(1.f, 1.f + e);
        }
    }
    __syncthreads();
#pragma unroll
    for (int it = 0; it < 8; ++it) {
        int idx = it * 256 + tid;
        int row = idx >> 5, c4 = idx & 31;
        *(float4*)(out + (size_t)(i0 + row) * N_ + j0 + c4 * 4) = *(const float4*)&os[row][c4 * 4];
    }
}

extern "C" void kernel_launch(void* const* d_in, const int* in_sizes, int n_in,
                              void* d_out, int out_size, void* d_ws, size_t ws_size,
                              hipStream_t stream) {
    const float* X  = (const float*)d_in[0];
    const float* A  = (const float*)d_in[1];
    const float* W1 = (const float*)d_in[2];
    const float* W2 = (const float*)d_in[3];
    float* out = (float*)d_out;

    short* XW1T = (short*)d_ws;                    // [H][N] bf16, 2 MB
    short* ZPT  = XW1T + (size_t)H_ * N_;          // [L][N] bf16, 512 KB
    short* Z    = ZPT + (size_t)L_ * N_;           // [N][L] bf16, 512 KB
    float* P4   = (float*)(Z + (size_t)N_ * L_);   // [4][N][H] fp32, 16 MB
    float* Q4   = P4 + (size_t)4 * N_ * H_;        // [4][N][L] fp32, 4 MB
    short* Ab   = (short*)(Q4 + (size_t)4 * N_ * L_);  // [N][N] bf16, 134 MB

    size_t base = ((size_t)H_ * N_ + (size_t)L_ * N_ + (size_t)N_ * L_) * sizeof(short)
                + ((size_t)4 * N_ * H_ + (size_t)4 * N_ * L_) * sizeof(float);
    bool useAb = ws_size >= base + (size_t)N_ * N_ * sizeof(short);

    k1_xw1<<<N_ / 64, 256, 0, stream>>>(X, W1, XW1T);
    if (useAb)
        k2a<1><<<(N_ / 64) * KQN, 512, 0, stream>>>(A, XW1T, P4, Ab);
    else
        k2a<0><<<(N_ / 64) * KQN, 512, 0, stream>>>(A, XW1T, P4, Ab);
    k2b<<<N_ / 32, 256, 0, stream>>>(P4, W2, ZPT);
    if (useAb)
        k3a_bf<<<(N_ / 64) * KQN, 512, 0, stream>>>(Ab, ZPT, Q4);
    else
        k3a_f32<<<(N_ / 64) * KQN, 512, 0, stream>>>(A, ZPT, Q4);
    k3b<<<(N_ * L_) / (256 * 8), 256, 0, stream>>>(Q4, Z);
    k4_dec<<<(N_ / 64) * (N_ / 128), 256, 0, stream>>>(Z, out);
}

// Round 2
// 542.322 us; speedup vs baseline: 1.0334x; 1.0192x over previous
//
#include <hip/hip_runtime.h>
#include <hip/hip_bf16.h>

#define N_ 8192
#define F_ 256
#define H_ 128
#define L_ 32
#define TK 64
#define KQN 4
#define KQL (N_ / KQN)   // 2048

typedef __attribute__((ext_vector_type(8))) short bf16x8;
typedef __attribute__((ext_vector_type(4))) float f32x4;
typedef __attribute__((ext_vector_type(4))) short bf16x4;

// Raw barrier: flush LDS writes, do NOT drain vmcnt (prefetches stay in flight).
// __syncthreads() would emit s_waitcnt vmcnt(0) and kill the pipeline.
#define BAR() do { \
    asm volatile("s_waitcnt lgkmcnt(0)" ::: "memory"); \
    __builtin_amdgcn_s_barrier(); \
    __builtin_amdgcn_sched_barrier(0); \
} while (0)

// RNE float -> bf16 (finite inputs only)
__device__ __forceinline__ unsigned f2bf_u(float x) {
    unsigned u = __builtin_bit_cast(unsigned, x);
    return (u + 0x7fffu + ((u >> 16) & 1u)) >> 16;
}
__device__ __forceinline__ short f2bf(float x) { return (short)f2bf_u(x); }

__device__ __forceinline__ bf16x4 cvt4(float4 a) {
    bf16x4 v;
    v[0] = f2bf(a.x); v[1] = f2bf(a.y); v[2] = f2bf(a.z); v[3] = f2bf(a.w);
    return v;
}
__device__ __forceinline__ bf16x8 cvt8(float4 a, float4 b) {
    bf16x8 v;
    v[0] = f2bf(a.x); v[1] = f2bf(a.y); v[2] = f2bf(a.z); v[3] = f2bf(a.w);
    v[4] = f2bf(b.x); v[5] = f2bf(b.y); v[6] = f2bf(b.z); v[7] = f2bf(b.w);
    return v;
}

// ---------------------------------------------------------------------------
// k1: XW1T[n][i] = (X @ W1)[i][n], bf16.  64 rows/block, 4 waves x 16 rows.
// ---------------------------------------------------------------------------
__global__ __launch_bounds__(256) void k1_xw1(const float* __restrict__ X,
                                              const float* __restrict__ W1,
                                              short* __restrict__ XW1T) {
    __shared__ short w1t[H_ * (F_ + 8)];
    const int tid = threadIdx.x;
    for (int idx = tid; idx < F_ * H_; idx += 256) {
        int k = idx >> 7, n = idx & 127;
        w1t[n * (F_ + 8) + k] = f2bf(W1[idx]);
    }
    __syncthreads();
    const int wv = tid >> 6, l = tid & 63;
    const int lm = l & 15, q = l >> 4;
    const int i0 = blockIdx.x * 64 + wv * 16;
    const float* xrow = X + (size_t)(i0 + lm) * F_;
    f32x4 acc[8];
#pragma unroll
    for (int j = 0; j < 8; ++j) acc[j] = (f32x4){0.f, 0.f, 0.f, 0.f};
#pragma unroll
    for (int k0 = 0; k0 < F_; k0 += 32) {
        float4 a0 = *(const float4*)(xrow + k0 + q * 8);
        float4 a1 = *(const float4*)(xrow + k0 + q * 8 + 4);
        bf16x8 af = cvt8(a0, a1);
#pragma unroll
        for (int j = 0; j < 8; ++j) {
            bf16x8 bf = *(const bf16x8*)&w1t[(j * 16 + lm) * (F_ + 8) + k0 + q * 8];
            acc[j] = __builtin_amdgcn_mfma_f32_16x16x32_bf16(af, bf, acc[j], 0, 0, 0);
        }
    }
#pragma unroll
    for (int j = 0; j < 8; ++j) {
        bf16x4 o;
        o[0] = f2bf(acc[j][0]); o[1] = f2bf(acc[j][1]);
        o[2] = f2bf(acc[j][2]); o[3] = f2bf(acc[j][3]);
        *(bf16x4*)(XW1T + (size_t)(j * 16 + lm) * N_ + i0 + q * 4) = o;
    }
}

// ---------------------------------------------------------------------------
// k2a: P4[kq][i][n] += A[i, kq-slice] @ XW1[kq-slice, n]  (fp32 partials)
// 512 blocks = 128 row-tiles(64) x 4 K-quarters; 8 waves.
// Two reg sets, loads issued ~1.5 phases early; raw barriers keep them in
// flight (counted vmcnt at first use, compiler-managed).
// WRITE_AB: also stream out bf16 copy of A (for k3a to reuse, L3-resident).
// ---------------------------------------------------------------------------
template <int WRITE_AB>
__global__ __launch_bounds__(512) void k2a(const float* __restrict__ A,
                                           const short* __restrict__ XW1T,
                                           float* __restrict__ P4,
                                           short* __restrict__ Ab) {
    __shared__ short As[2][64][72];    // 18.4 KB
    __shared__ short Bs[2][128][72];   // 36.9 KB
    const int tid = threadIdx.x;
    const int bi = blockIdx.x >> 2, kq = blockIdx.x & 3;
    const int i0 = bi * 64, kbase = kq * KQL;
    // staging coords: A 64x64 fp32, thread does rows ar, ar+32 (float4 each)
    const int ar = tid >> 4, ac = (tid & 15) * 4;
    // B 128x64 bf16, thread does rows br, br+64 (bf16x8 each)
    const int br = tid >> 3, bc = (tid & 7) * 8;
    const float* Ap = A + (size_t)(i0 + ar) * N_ + kbase + ac;
    const short* Bp = XW1T + (size_t)br * N_ + kbase + bc;
    short* Abp = Ab + (size_t)(i0 + ar) * N_ + kbase + ac;

    const int wv = tid >> 6, l = tid & 63, lm = l & 15, q = l >> 4;
    const int rg = wv & 3, ch = wv >> 2;   // 4 row-groups x 2 col-halves

    float4 Pa0, Pa1; bf16x8 Pb0, Pb1;   // reg set P
    float4 Qa0, Qa1; bf16x8 Qb0, Qb1;   // reg set Q

#define LOADG2(S, o_) do { size_t _o = (size_t)(o_) * TK; \
        S##a0 = *(const float4*)(Ap + _o); \
        S##a1 = *(const float4*)(Ap + _o + (size_t)32 * N_); \
        S##b0 = *(const bf16x8*)(Bp + _o); \
        S##b1 = *(const bf16x8*)(Bp + _o + (size_t)64 * N_); } while (0)
#define STORES2(S, b_, o_) do { \
        bf16x4 _c0 = cvt4(S##a0), _c1 = cvt4(S##a1); \
        *(bf16x4*)&As[b_][ar][ac] = _c0; \
        *(bf16x4*)&As[b_][ar + 32][ac] = _c1; \
        *(bf16x8*)&Bs[b_][br][bc] = S##b0; \
        *(bf16x8*)&Bs[b_][br + 64][bc] = S##b1; \
        if (WRITE_AB) { size_t _o = (size_t)(o_) * TK; \
            *(bf16x4*)(Abp + _o) = _c0; \
            *(bf16x4*)(Abp + _o + (size_t)32 * N_) = _c1; } } while (0)
#define MFMAPH2(b_) do { \
        for (int kh = 0; kh < 2; ++kh) { \
            bf16x8 af = *(const bf16x8*)&As[b_][rg * 16 + lm][kh * 32 + q * 8]; \
            for (int jt = 0; jt < 4; ++jt) { \
                bf16x8 bfv = *(const bf16x8*)&Bs[b_][ch * 64 + jt * 16 + lm][kh * 32 + q * 8]; \
                acc[jt] = __builtin_amdgcn_mfma_f32_16x16x32_bf16(af, bfv, acc[jt], 0, 0, 0); \
            } } } while (0)

    LOADG2(P, 0); STORES2(P, 0, 0); LOADG2(Q, 1);
    BAR();

    f32x4 acc[4];
#pragma unroll
    for (int j = 0; j < 4; ++j) acc[j] = (f32x4){0.f, 0.f, 0.f, 0.f};
    const int NS = KQL / TK;   // 32
    for (int s = 0; s < NS; s += 2) {
        if (s + 2 < NS) LOADG2(P, s + 2);
        MFMAPH2(0);
        STORES2(Q, 1, s + 1);
        BAR();
        if (s + 3 < NS) LOADG2(Q, s + 3);
        MFMAPH2(1);
        if (s + 2 < NS) STORES2(P, 0, s + 2);
        BAR();
    }
#undef LOADG2
#undef STORES2
#undef MFMAPH2
    // store partials: row = i0+rg*16+q*4+r, col = ch*64+jt*16+lm
    float* Pb = P4 + ((size_t)kq * N_ + i0 + rg * 16 + q * 4) * H_ + ch * 64 + lm;
#pragma unroll
    for (int jt = 0; jt < 4; ++jt)
#pragma unroll
        for (int r = 0; r < 4; ++r)
            Pb[(size_t)r * H_ + jt * 16] = acc[jt][r];
}

// ---------------------------------------------------------------------------
// k2b: ZPT[j][i] = ((relu(sum_kq P4)) @ W2)[i][j], bf16. 32 rows/block.
// ---------------------------------------------------------------------------
__global__ __launch_bounds__(256) void k2b(const float* __restrict__ P4,
                                           const float* __restrict__ W2,
                                           short* __restrict__ ZPT) {
    __shared__ short hl[32][136];
    __shared__ short w2t[32][136];
    const int tid = threadIdx.x;
    for (int idx = tid; idx < H_ * L_; idx += 256) {
        int k = idx >> 5, j = idx & 31;
        w2t[j][k] = f2bf(W2[idx]);
    }
    const int i0 = blockIdx.x * 32;
    const int r = tid >> 3, c16 = (tid & 7) * 16;
    float4 v[4];
#pragma unroll
    for (int cc = 0; cc < 4; ++cc) v[cc] = (float4){0.f, 0.f, 0.f, 0.f};
#pragma unroll
    for (int kq = 0; kq < 4; ++kq) {
        const float* p = P4 + ((size_t)kq * N_ + i0 + r) * H_ + c16;
#pragma unroll
        for (int cc = 0; cc < 4; ++cc) {
            float4 t = *(const float4*)(p + cc * 4);
            v[cc].x += t.x; v[cc].y += t.y; v[cc].z += t.z; v[cc].w += t.w;
        }
    }
#pragma unroll
    for (int cc = 0; cc < 4; ++cc) {
        v[cc].x = v[cc].x > 0.f ? v[cc].x : 0.f;
        v[cc].y = v[cc].y > 0.f ? v[cc].y : 0.f;
        v[cc].z = v[cc].z > 0.f ? v[cc].z : 0.f;
        v[cc].w = v[cc].w > 0.f ? v[cc].w : 0.f;
    }
    *(bf16x8*)&hl[r][c16] = cvt8(v[0], v[1]);
    *(bf16x8*)&hl[r][c16 + 8] = cvt8(v[2], v[3]);
    __syncthreads();
    const int wv = tid >> 6, l = tid & 63, lm = l & 15, q = l >> 4;
    const int ti = wv & 1, tj = wv >> 1;
    f32x4 a2 = (f32x4){0.f, 0.f, 0.f, 0.f};
#pragma unroll
    for (int k0 = 0; k0 < H_; k0 += 32) {
        bf16x8 af = *(const bf16x8*)&hl[ti * 16 + lm][k0 + q * 8];
        bf16x8 bf = *(const bf16x8*)&w2t[tj * 16 + lm][k0 + q * 8];
        a2 = __builtin_amdgcn_mfma_f32_16x16x32_bf16(af, bf, a2, 0, 0, 0);
    }
    bf16x4 o;
    o[0] = f2bf(a2[0]); o[1] = f2bf(a2[1]); o[2] = f2bf(a2[2]); o[3] = f2bf(a2[3]);
    *(bf16x4*)(ZPT + (size_t)(tj * 16 + lm) * N_ + i0 + ti * 16 + q * 4) = o;
}

// ---------------------------------------------------------------------------
// k3a_bf: Q4[kq][i][j] += Ab[i, kq-slice] @ ZP[kq-slice, j]; A already bf16.
// Same raw-barrier pipelined schedule as k2a.
// ---------------------------------------------------------------------------
__global__ __launch_bounds__(512) void k3a_bf(const short* __restrict__ Ab,
                                              const short* __restrict__ ZPT,
                                              float* __restrict__ Q4) {
    __shared__ short As[2][64][72];   // 18.4 KB
    __shared__ short Bs[2][32][72];   // 9.2 KB
    const int tid = threadIdx.x;
    const int bi = blockIdx.x >> 2, kq = blockIdx.x & 3;
    const int i0 = bi * 64, kbase = kq * KQL;
    const int ar8 = tid >> 3, ac8 = (tid & 7) * 8;   // A: 64 rows x 64 bf16, bf16x8 each
    const int br = tid >> 4, bc = (tid & 15) * 4;    // B: 32 rows x 64 bf16, bf16x4 each
    const short* Ap = Ab + (size_t)(i0 + ar8) * N_ + kbase + ac8;
    const short* Bp = ZPT + (size_t)br * N_ + kbase + bc;

    const int wv = tid >> 6, l = tid & 63, lm = l & 15, q = l >> 4;
    const int rg = wv & 3, ch = wv >> 2;   // 4 row-groups x 2 col-halves(16)

    bf16x8 Pa; bf16x4 Pb;
    bf16x8 Qa; bf16x4 Qb;

#define LOADG3(S, o_) do { size_t _o = (size_t)(o_) * TK; \
        S##a = *(const bf16x8*)(Ap + _o); \
        S##b = *(const bf16x4*)(Bp + _o); } while (0)
#define STORES3(S, b_) do { \
        *(bf16x8*)&As[b_][ar8][ac8] = S##a; \
        *(bf16x4*)&Bs[b_][br][bc] = S##b; } while (0)
#define MFMAPH3(b_) do { \
        for (int kh = 0; kh < 2; ++kh) { \
            bf16x8 af = *(const bf16x8*)&As[b_][rg * 16 + lm][kh * 32 + q * 8]; \
            bf16x8 bfv = *(const bf16x8*)&Bs[b_][ch * 16 + lm][kh * 32 + q * 8]; \
            acc = __builtin_amdgcn_mfma_f32_16x16x32_bf16(af, bfv, acc, 0, 0, 0); \
        } } while (0)

    LOADG3(P, 0); STORES3(P, 0); LOADG3(Q, 1);
    BAR();

    f32x4 acc = (f32x4){0.f, 0.f, 0.f, 0.f};
    const int NS = KQL / TK;   // 32
    for (int s = 0; s < NS; s += 2) {
        if (s + 2 < NS) LOADG3(P, s + 2);
        MFMAPH3(0);
        STORES3(Q, 1);
        BAR();
        if (s + 3 < NS) LOADG3(Q, s + 3);
        MFMAPH3(1);
        if (s + 2 < NS) STORES3(P, 0);
        BAR();
    }
#undef LOADG3
#undef STORES3
#undef MFMAPH3
    float* Qb_ = Q4 + ((size_t)kq * N_ + i0 + rg * 16 + q * 4) * L_ + ch * 16 + lm;
#pragma unroll
    for (int r = 0; r < 4; ++r)
        Qb_[(size_t)r * L_] = acc[r];
}

// ---------------------------------------------------------------------------
// k3a_f32: fallback (workspace too small for Ab) — reads fp32 A.
// ---------------------------------------------------------------------------
__global__ __launch_bounds__(512) void k3a_f32(const float* __restrict__ A,
                                               const short* __restrict__ ZPT,
                                               float* __restrict__ Q4) {
    __shared__ short As[2][64][72];
    __shared__ short Bs[2][32][72];
    const int tid = threadIdx.x;
    const int bi = blockIdx.x >> 2, kq = blockIdx.x & 3;
    const int i0 = bi * 64, kbase = kq * KQL;
    const int ar = tid >> 4, ac = (tid & 15) * 4;
    const int br = tid >> 4, bc = (tid & 15) * 4;
    const float* Ap = A + (size_t)(i0 + ar) * N_ + kbase + ac;
    const short* Bp = ZPT + (size_t)br * N_ + kbase + bc;

    const int wv = tid >> 6, l = tid & 63, lm = l & 15, q = l >> 4;
    const int rg = wv & 3, ch = wv >> 2;

    float4 pa0, pa1; bf16x4 pb0;
#define LOADG0(s) do { size_t o = (size_t)(s) * TK; \
        pa0 = *(const float4*)(Ap + o); \
        pa1 = *(const float4*)(Ap + o + (size_t)32 * N_); \
        pb0 = *(const bf16x4*)(Bp + o); } while (0)
#define STORES0(b) do { \
        *(bf16x4*)&As[b][ar][ac] = cvt4(pa0); \
        *(bf16x4*)&As[b][ar + 32][ac] = cvt4(pa1); \
        *(bf16x4*)&Bs[b][br][bc] = pb0; } while (0)

    LOADG0(0); STORES0(0); LOADG0(1);
    BAR();

    f32x4 acc = (f32x4){0.f, 0.f, 0.f, 0.f};
    const int NS = KQL / TK;
#pragma unroll 2
    for (int s = 0; s < NS; ++s) {
        const int b = s & 1;
#pragma unroll
        for (int kh = 0; kh < 2; ++kh) {
            bf16x8 af = *(const bf16x8*)&As[b][rg * 16 + lm][kh * 32 + q * 8];
            bf16x8 bfv = *(const bf16x8*)&Bs[b][ch * 16 + lm][kh * 32 + q * 8];
            acc = __builtin_amdgcn_mfma_f32_16x16x32_bf16(af, bfv, acc, 0, 0, 0);
        }
        if (s + 1 < NS) {
            STORES0((s + 1) & 1);
            if (s + 2 < NS) LOADG0(s + 2);
        }
        BAR();
    }
#undef LOADG0
#undef STORES0
    float* Qb = Q4 + ((size_t)kq * N_ + i0 + rg * 16 + q * 4) * L_ + ch * 16 + lm;
#pragma unroll
    for (int r = 0; r < 4; ++r)
        Qb[(size_t)r * L_] = acc[r];
}

// ---------------------------------------------------------------------------
// k3b: Z = bf16(sum_kq Q4), flat elementwise.
// ---------------------------------------------------------------------------
__global__ __launch_bounds__(256) void k3b(const float* __restrict__ Q4,
                                           short* __restrict__ Z) {
    size_t g = ((size_t)blockIdx.x * 256 + threadIdx.x) * 8;
    float4 s0 = (float4){0.f, 0.f, 0.f, 0.f}, s1 = s0;
#pragma unroll
    for (int kq = 0; kq < 4; ++kq) {
        const float* p = Q4 + (size_t)kq * N_ * L_ + g;
        float4 a = *(const float4*)(p);
        float4 b = *(const float4*)(p + 4);
        s0.x += a.x; s0.y += a.y; s0.z += a.z; s0.w += a.w;
        s1.x += b.x; s1.y += b.y; s1.z += b.z; s1.w += b.w;
    }
    *(bf16x8*)(Z + g) = cvt8(s0, s1);
}

// ---------------------------------------------------------------------------
// k4: out = sigmoid(Z @ Z^T). 64x128/block (33.8 KB LDS -> 4 blocks/CU);
// sigmoid -> LDS -> coalesced float4 stores.
// ---------------------------------------------------------------------------
__global__ __launch_bounds__(256) void k4_dec(const short* __restrict__ Z,
                                              float* __restrict__ out) {
    __shared__ float os[64][132];   // 33.8 KB
    const int tid = threadIdx.x;
    const int wv = tid >> 6, l = tid & 63;
    const int lm = l & 15, q = l >> 4;
    const int bj = blockIdx.x & 63, bi = blockIdx.x >> 6;
    const int i0 = bi * 64, j0 = bj * 128;
    bf16x8 af = *(const bf16x8*)(Z + (size_t)(i0 + wv * 16 + lm) * L_ + q * 8);
#pragma unroll
    for (int tj = 0; tj < 8; ++tj) {
        bf16x8 bfv = *(const bf16x8*)(Z + (size_t)(j0 + tj * 16 + lm) * L_ + q * 8);
        f32x4 c = __builtin_amdgcn_mfma_f32_16x16x32_bf16(
            af, bfv, (f32x4){0.f, 0.f, 0.f, 0.f}, 0, 0, 0);
#pragma unroll
        for (int r = 0; r < 4; ++r) {
            float e = __expf(-c[r]);
            os[wv * 16 + q * 4 + r][tj * 16 + lm] = __fdividef(1.f, 1.f + e);
        }
    }
    __syncthreads();
#pragma unroll
    for (int it = 0; it < 8; ++it) {
        int idx = it * 256 + tid;
        int row = idx >> 5, c4 = idx & 31;
        *(float4*)(out + (size_t)(i0 + row) * N_ + j0 + c4 * 4) = *(const float4*)&os[row][c4 * 4];
    }
}

extern "C" void kernel_launch(void* const* d_in, const int* in_sizes, int n_in,
                              void* d_out, int out_size, void* d_ws, size_t ws_size,
                              hipStream_t stream) {
    const float* X  = (const float*)d_in[0];
    const float* A  = (const float*)d_in[1];
    const float* W1 = (const float*)d_in[2];
    const float* W2 = (const float*)d_in[3];
    float* out = (float*)d_out;

    short* XW1T = (short*)d_ws;                    // [H][N] bf16, 2 MB
    short* ZPT  = XW1T + (size_t)H_ * N_;          // [L][N] bf16, 512 KB
    short* Z    = ZPT + (size_t)L_ * N_;           // [N][L] bf16, 512 KB
    float* P4   = (float*)(Z + (size_t)N_ * L_);   // [4][N][H] fp32, 16 MB
    float* Q4   = P4 + (size_t)4 * N_ * H_;        // [4][N][L] fp32, 4 MB
    short* Ab   = (short*)(Q4 + (size_t)4 * N_ * L_);  // [N][N] bf16, 134 MB

    size_t base = ((size_t)H_ * N_ + (size_t)L_ * N_ + (size_t)N_ * L_) * sizeof(short)
                + ((size_t)4 * N_ * H_ + (size_t)4 * N_ * L_) * sizeof(float);
    bool useAb = ws_size >= base + (size_t)N_ * N_ * sizeof(short);

    k1_xw1<<<N_ / 64, 256, 0, stream>>>(X, W1, XW1T);
    if (useAb)
        k2a<1><<<(N_ / 64) * KQN, 512, 0, stream>>>(A, XW1T, P4, Ab);
    else
        k2a<0><<<(N_ / 64) * KQN, 512, 0, stream>>>(A, XW1T, P4, Ab);
    k2b<<<N_ / 32, 256, 0, stream>>>(P4, W2, ZPT);
    if (useAb)
        k3a_bf<<<(N_ / 64) * KQN, 512, 0, stream>>>(Ab, ZPT, Q4);
    else
        k3a_f32<<<(N_ / 64) * KQN, 512, 0, stream>>>(A, ZPT, Q4);
    k3b<<<(N_ * L_) / (256 * 8), 256, 0, stream>>>(Q4, Z);
    k4_dec<<<(N_ / 64) * (N_ / 128), 256, 0, stream>>>(Z, out);
}